// Round 23
// baseline (48.603 us; speedup 1.0000x reference)
//
#include <hip/hip_runtime.h>
#include <hip/hip_bf16.h>

// Problem constants
#define NB 4
#define SEQ 2048
#define DM 1024
#define DH 64

typedef __attribute__((ext_vector_type(8))) short bf16x8;
typedef __attribute__((ext_vector_type(4))) float f32x4;
typedef __attribute__((ext_vector_type(4))) short short4v;

__device__ inline short f2bf(float f) {
  union { float f; unsigned u; } x; x.f = f;
  unsigned r = x.u + 0x7FFFu + ((x.u >> 16) & 1u);
  return (short)(r >> 16);
}

// ---------------------------------------------------------------------------
// Kernel 0: W fp32 -> bf16, once. wbf[192][1024]: rows 0-63 Wq, 64-127 Wk,
// 128-191 Wv.
// ---------------------------------------------------------------------------
__global__ __launch_bounds__(256) void wconv_kernel(
    const float* __restrict__ Wq, const float* __restrict__ Wk,
    const float* __restrict__ Wv, short* __restrict__ wbf)
{
  const int tid = blockIdx.x * 256 + threadIdx.x;
  const int base = tid * 8;
  const int row = base >> 10;          // 0..191
  const int col = base & 1023;
  const float* src = (row < 64) ? Wq : (row < 128) ? Wk : Wv;
  src += (size_t)(row & 63) * DM + col;
  f32x4 f0 = ((const f32x4*)src)[0];
  f32x4 f1 = ((const f32x4*)src)[1];
  bf16x8 h = { f2bf(f0[0]), f2bf(f0[1]), f2bf(f0[2]), f2bf(f0[3]),
               f2bf(f1[0]), f2bf(f1[1]), f2bf(f1[2]), f2bf(f1[3]) };
  *(bf16x8*)(wbf + (size_t)row * DM + col) = h;
}

// ---------------------------------------------------------------------------
// Kernel 1: QKV projection — BK=128 variant (8 iters, HALF the barrier
// drains of R22's BK=64/16-iter config; no occupancy cost since already
// 1 block/CU). Depth-2 reg ping-pong; 256 blocks x 512 threads, 32x192
// tile. LDS 122KB (stride 136 shorts = 272B row: 4 banks/row advance ->
// 16 frag-rows span 8 positions = free 2-way). Vectorized V^T epilogue.
// ---------------------------------------------------------------------------
__global__ __launch_bounds__(512) void proj_kernel(
    const float* __restrict__ X, const short* __restrict__ wbf,
    short* __restrict__ qout, short* __restrict__ kout,
    short* __restrict__ vtout)
{
  __shared__ short x_lds[2][32][136];
  __shared__ short w_lds[2][192][136];

  const int t = threadIdx.x;
  const int l = t & 63;
  const int w = t >> 6;                 // 0..7
  const int m0 = blockIdx.x * 32;

  f32x4 acc[3];
#pragma unroll
  for (int i = 0; i < 3; i++) acc[i] = (f32x4){0.f, 0.f, 0.f, 0.f};

  const int xr = t >> 4;                // 0..31
  const int xc = (t & 15) * 8;          // float cols 0..120 (8 per thread)
  const int wr = t >> 3;                // 0..63
  const int wc = (t & 7) * 16;          // bf16 cols 0..112 (16 per thread)

  const float* xsrc  = X   + (size_t)(m0 + xr) * DM + xc;
  const short* wsrc0 = wbf + (size_t)(wr)       * DM + wc;
  const short* wsrc1 = wbf + (size_t)(64 + wr)  * DM + wc;
  const short* wsrc2 = wbf + (size_t)(128 + wr) * DM + wc;

  // prologue: stage k-chunk 0 (cols 0-127) into buf0
  {
    f32x4 f0 = ((const f32x4*)xsrc)[0];
    f32x4 f1 = ((const f32x4*)xsrc)[1];
    bf16x8 hx = { f2bf(f0[0]), f2bf(f0[1]), f2bf(f0[2]), f2bf(f0[3]),
                  f2bf(f1[0]), f2bf(f1[1]), f2bf(f1[2]), f2bf(f1[3]) };
    *(bf16x8*)&x_lds[0][xr][xc] = hx;
    *(bf16x8*)&w_lds[0][wr][wc]            = *(const bf16x8*)wsrc0;
    *(bf16x8*)&w_lds[0][wr][wc + 8]        = *(const bf16x8*)(wsrc0 + 8);
    *(bf16x8*)&w_lds[0][64 + wr][wc]       = *(const bf16x8*)wsrc1;
    *(bf16x8*)&w_lds[0][64 + wr][wc + 8]   = *(const bf16x8*)(wsrc1 + 8);
    *(bf16x8*)&w_lds[0][128 + wr][wc]      = *(const bf16x8*)wsrc2;
    *(bf16x8*)&w_lds[0][128 + wr][wc + 8]  = *(const bf16x8*)(wsrc2 + 8);
  }
  // issue k-chunk 1 loads into rA (in flight across the barrier)
  f32x4 xA0 = ((const f32x4*)(xsrc + 128))[0];
  f32x4 xA1 = ((const f32x4*)(xsrc + 128))[1];
  bf16x8 wA0 = *(const bf16x8*)(wsrc0 + 128);
  bf16x8 wA1 = *(const bf16x8*)(wsrc0 + 136);
  bf16x8 wA2 = *(const bf16x8*)(wsrc1 + 128);
  bf16x8 wA3 = *(const bf16x8*)(wsrc1 + 136);
  bf16x8 wA4 = *(const bf16x8*)(wsrc2 + 128);
  bf16x8 wA5 = *(const bf16x8*)(wsrc2 + 136);
  f32x4 xB0, xB1;
  bf16x8 wB0, wB1, wB2, wB3, wB4, wB5;
  __syncthreads();

#pragma unroll
  for (int it = 0; it < 8; it++) {
    const int buf = it & 1;
    const int k2 = (it + 2) * 128;

    // issue loads for iter it+2 (static ping-pong: even->rB, odd->rA)
    if ((it & 1) == 0) {
      if (it + 2 < 8) {
        xB0 = ((const f32x4*)(xsrc + k2))[0];
        xB1 = ((const f32x4*)(xsrc + k2))[1];
        wB0 = *(const bf16x8*)(wsrc0 + k2);
        wB1 = *(const bf16x8*)(wsrc0 + k2 + 8);
        wB2 = *(const bf16x8*)(wsrc1 + k2);
        wB3 = *(const bf16x8*)(wsrc1 + k2 + 8);
        wB4 = *(const bf16x8*)(wsrc2 + k2);
        wB5 = *(const bf16x8*)(wsrc2 + k2 + 8);
      }
    } else {
      if (it + 2 < 8) {
        xA0 = ((const f32x4*)(xsrc + k2))[0];
        xA1 = ((const f32x4*)(xsrc + k2))[1];
        wA0 = *(const bf16x8*)(wsrc0 + k2);
        wA1 = *(const bf16x8*)(wsrc0 + k2 + 8);
        wA2 = *(const bf16x8*)(wsrc1 + k2);
        wA3 = *(const bf16x8*)(wsrc1 + k2 + 8);
        wA4 = *(const bf16x8*)(wsrc2 + k2);
        wA5 = *(const bf16x8*)(wsrc2 + k2 + 8);
      }
    }

    // compute from lds[buf]: 4 k-frags of 32 per iteration
    {
      const int arow = (w & 1) * 16 + (l & 15);
      const int kk = (l >> 4) << 3;
#pragma unroll
      for (int ks = 0; ks < 4; ks++) {
        bf16x8 a = *(const bf16x8*)&x_lds[buf][arow][ks * 32 + kk];
#pragma unroll
        for (int nf = 0; nf < 3; nf++) {
          const int cf = (w >> 1) * 3 + nf;
          bf16x8 b = *(const bf16x8*)&w_lds[buf][cf * 16 + (l & 15)][ks * 32 + kk];
          acc[nf] = __builtin_amdgcn_mfma_f32_16x16x32_bf16(a, b, acc[nf], 0, 0, 0);
        }
      }
    }

    // ds_write iter it+1's regs (issued one full iteration ago)
    if (it < 7) {
      if ((it & 1) == 0) {
        bf16x8 hx = { f2bf(xA0[0]), f2bf(xA0[1]), f2bf(xA0[2]), f2bf(xA0[3]),
                      f2bf(xA1[0]), f2bf(xA1[1]), f2bf(xA1[2]), f2bf(xA1[3]) };
        *(bf16x8*)&x_lds[buf ^ 1][xr][xc] = hx;
        *(bf16x8*)&w_lds[buf ^ 1][wr][wc]           = wA0;
        *(bf16x8*)&w_lds[buf ^ 1][wr][wc + 8]       = wA1;
        *(bf16x8*)&w_lds[buf ^ 1][64 + wr][wc]      = wA2;
        *(bf16x8*)&w_lds[buf ^ 1][64 + wr][wc + 8]  = wA3;
        *(bf16x8*)&w_lds[buf ^ 1][128 + wr][wc]     = wA4;
        *(bf16x8*)&w_lds[buf ^ 1][128 + wr][wc + 8] = wA5;
      } else {
        bf16x8 hx = { f2bf(xB0[0]), f2bf(xB0[1]), f2bf(xB0[2]), f2bf(xB0[3]),
                      f2bf(xB1[0]), f2bf(xB1[1]), f2bf(xB1[2]), f2bf(xB1[3]) };
        *(bf16x8*)&x_lds[buf ^ 1][xr][xc] = hx;
        *(bf16x8*)&w_lds[buf ^ 1][wr][wc]           = wB0;
        *(bf16x8*)&w_lds[buf ^ 1][wr][wc + 8]       = wB1;
        *(bf16x8*)&w_lds[buf ^ 1][64 + wr][wc]      = wB2;
        *(bf16x8*)&w_lds[buf ^ 1][64 + wr][wc + 8]  = wB3;
        *(bf16x8*)&w_lds[buf ^ 1][128 + wr][wc]     = wB4;
        *(bf16x8*)&w_lds[buf ^ 1][128 + wr][wc + 8] = wB5;
      }
    }
    __syncthreads();
  }

  // epilogue: C row=(lane>>4)*4+reg, col=cf*16+(lane&15)  [m89]
  const int rowb = m0 + (w & 1) * 16 + ((l >> 4) << 2);
#pragma unroll
  for (int nf = 0; nf < 3; nf++) {
    const int c = ((w >> 1) * 3 + nf) * 16 + (l & 15);
    if (c < 64) {
#pragma unroll
      for (int j = 0; j < 4; j++)
        qout[(rowb + j) * DH + c] = f2bf(acc[nf][j] * 0.03125f);  // 1/32
    } else if (c < 128) {
#pragma unroll
      for (int j = 0; j < 4; j++)
        kout[(rowb + j) * DH + (c - 64)] = f2bf(acc[nf][j]);
    } else {
      // V^T: regs j=0..3 are rows rowb..rowb+3 -> one 8B store.
      const int b = rowb >> 11, s = rowb & (SEQ - 1);
      short4v h = { f2bf(acc[nf][0]), f2bf(acc[nf][1]),
                    f2bf(acc[nf][2]), f2bf(acc[nf][3]) };
      *(short4v*)(vtout + (size_t)b * DH * SEQ + (size_t)(c - 128) * SEQ + s) = h;
    }
  }
}

// ---------------------------------------------------------------------------
// Kernel 2: split-KV causal flash (R22 verbatim; nck=4/cht=8).
// ---------------------------------------------------------------------------
__global__ __launch_bounds__(256) void flash_kernel(
    const short* __restrict__ qin, const short* __restrict__ kin,
    const short* __restrict__ vtin, float* __restrict__ po,
    float* __restrict__ pm, float* __restrict__ pl,
    const int nck, const int cht)
{
  __shared__ short k_lds[2][64][72];
  __shared__ short vt_lds[2][64][72];
  __shared__ short p_lds[4][16][72];

  const int qt = blockIdx.x;
  const int ck = blockIdx.y;
  const int t0 = ck * cht;
  if (t0 > qt) return;
  const int b = blockIdx.z;

  const int t = threadIdx.x;
  const int l = t & 63;
  const int w = t >> 6;
  const int q0 = qt * 64;
  const int tend = min(t0 + cht, qt + 1);

  const short* qb = qin  + (size_t)b * SEQ * DH;
  const short* kb = kin  + (size_t)b * SEQ * DH;
  const short* vb = vtin + (size_t)b * DH * SEQ;

  const short* qr = qb + (size_t)(q0 + w * 16 + (l & 15)) * DH + ((l >> 4) << 3);
  const bf16x8 qf0 = *(const bf16x8*)qr;
  const bf16x8 qf1 = *(const bf16x8*)(qr + 32);

  f32x4 o[4];
#pragma unroll
  for (int i = 0; i < 4; i++) o[i] = (f32x4){0.f, 0.f, 0.f, 0.f};
  float m_run[4] = {-1e30f, -1e30f, -1e30f, -1e30f};
  float l_run[4] = {0.f, 0.f, 0.f, 0.f};

  const int sr = t >> 3;
  const int sc = (t & 7) * 8;

  {
    const int j0 = t0 * 64;
#pragma unroll
    for (int i = 0; i < 2; i++) {
      const int r = sr + i * 32;
      *(bf16x8*)&k_lds[0][r][sc]  = *(const bf16x8*)(kb + (size_t)(j0 + r) * DH + sc);
      *(bf16x8*)&vt_lds[0][r][sc] = *(const bf16x8*)(vb + (size_t)r * SEQ + j0 + sc);
    }
  }
  __syncthreads();

  for (int tt = t0; tt < tend; tt++) {
    const int bi = (tt - t0) & 1;
    const int j0 = tt * 64;
    const bool pf = (tt + 1 < tend);

    bf16x8 kpf0, kpf1, vpf0, vpf1;
    if (pf) {
      const int j1 = j0 + 64;
      kpf0 = *(const bf16x8*)(kb + (size_t)(j1 + sr) * DH + sc);
      kpf1 = *(const bf16x8*)(kb + (size_t)(j1 + sr + 32) * DH + sc);
      vpf0 = *(const bf16x8*)(vb + (size_t)sr * SEQ + j1 + sc);
      vpf1 = *(const bf16x8*)(vb + (size_t)(sr + 32) * SEQ + j1 + sc);
    }

    f32x4 s[4];
#pragma unroll
    for (int nf = 0; nf < 4; nf++) {
      const short* kr = &k_lds[bi][nf * 16 + (l & 15)][(l >> 4) << 3];
      bf16x8 b0 = *(const bf16x8*)kr;
      bf16x8 b1 = *(const bf16x8*)(kr + 32);
      f32x4 a = (f32x4){0.f, 0.f, 0.f, 0.f};
      a = __builtin_amdgcn_mfma_f32_16x16x32_bf16(qf0, b0, a, 0, 0, 0);
      a = __builtin_amdgcn_mfma_f32_16x16x32_bf16(qf1, b1, a, 0, 0, 0);
      s[nf] = a;
    }

    {
      const int growb = q0 + w * 16 + ((l >> 4) << 2);
#pragma unroll
      for (int nf = 0; nf < 4; nf++) {
        const int gcol = j0 + nf * 16 + (l & 15);
#pragma unroll
        for (int j = 0; j < 4; j++)
          if (gcol > growb + j) s[nf][j] = -1e30f;
      }
    }

    float alpha[4];
#pragma unroll
    for (int j = 0; j < 4; j++) {
      float tm = fmaxf(fmaxf(s[0][j], s[1][j]), fmaxf(s[2][j], s[3][j]));
      tm = fmaxf(tm, __shfl_xor(tm, 1));
      tm = fmaxf(tm, __shfl_xor(tm, 2));
      tm = fmaxf(tm, __shfl_xor(tm, 4));
      tm = fmaxf(tm, __shfl_xor(tm, 8));
      const float mn = fmaxf(m_run[j], tm);
      alpha[j] = exp2f((m_run[j] - mn) * 1.44269504f);
      m_run[j] = mn;
      float rs = 0.f;
#pragma unroll
      for (int nf = 0; nf < 4; nf++) {
        const float p = exp2f((s[nf][j] - mn) * 1.44269504f);
        s[nf][j] = p;
        rs += p;
      }
      rs += __shfl_xor(rs, 1);
      rs += __shfl_xor(rs, 2);
      rs += __shfl_xor(rs, 4);
      rs += __shfl_xor(rs, 8);
      l_run[j] = l_run[j] * alpha[j] + rs;
    }
#pragma unroll
    for (int df = 0; df < 4; df++)
#pragma unroll
      for (int j = 0; j < 4; j++) o[df][j] *= alpha[j];

#pragma unroll
    for (int nf = 0; nf < 4; nf++)
#pragma unroll
      for (int j = 0; j < 4; j++)
        p_lds[w][((l >> 4) << 2) + j][nf * 16 + (l & 15)] = f2bf(s[nf][j]);

    asm volatile("s_waitcnt lgkmcnt(0)" ::: "memory");
    __builtin_amdgcn_sched_barrier(0);

#pragma unroll
    for (int ks = 0; ks < 2; ks++) {
      const short* pr = &p_lds[w][l & 15][ks * 32 + ((l >> 4) << 3)];
      const bf16x8 pa = *(const bf16x8*)pr;
#pragma unroll
      for (int df = 0; df < 4; df++) {
        const short* vr = &vt_lds[bi][df * 16 + (l & 15)][ks * 32 + ((l >> 4) << 3)];
        const bf16x8 vf = *(const bf16x8*)vr;
        o[df] = __builtin_amdgcn_mfma_f32_16x16x32_bf16(pa, vf, o[df], 0, 0, 0);
      }
    }

    if (pf) {
      *(bf16x8*)&k_lds[bi ^ 1][sr][sc]       = kpf0;
      *(bf16x8*)&k_lds[bi ^ 1][sr + 32][sc]  = kpf1;
      *(bf16x8*)&vt_lds[bi ^ 1][sr][sc]      = vpf0;
      *(bf16x8*)&vt_lds[bi ^ 1][sr + 32][sc] = vpf1;
    }
    __syncthreads();
  }

  const int rowb = q0 + w * 16 + ((l >> 4) << 2);
#pragma unroll
  for (int j = 0; j < 4; j++) {
    const size_t rowg = (size_t)b * SEQ + rowb + j;
#pragma unroll
    for (int df = 0; df < 4; df++)
      po[(rowg * nck + ck) * DH + df * 16 + (l & 15)] = o[df][j];
    if ((l & 15) == 0) {
      pm[rowg * nck + ck] = m_run[j];
      pl[rowg * nck + ck] = l_run[j];
    }
  }
}

// ---------------------------------------------------------------------------
// Kernel 3: merge partials. ckshift = log2(cht*64).
// ---------------------------------------------------------------------------
__global__ __launch_bounds__(256) void merge_kernel(
    const float* __restrict__ po, const float* __restrict__ pm,
    const float* __restrict__ pl, float* __restrict__ out,
    const int nck, const int ckshift)
{
  const int gid = blockIdx.x * 256 + threadIdx.x;
  const int r = gid >> 6;
  const int d = gid & 63;
  const int s = r & (SEQ - 1);
  const int C = (s >> ckshift) + 1;

  float m = -1e30f;
  for (int c = 0; c < C; c++) m = fmaxf(m, pm[r * nck + c]);
  float den = 0.f, num = 0.f;
  for (int c = 0; c < C; c++) {
    const float wgt = exp2f((pm[r * nck + c] - m) * 1.44269504f);
    den += pl[r * nck + c] * wgt;
    num += po[(size_t)(r * nck + c) * DH + d] * wgt;
  }
  out[gid] = num / den;
}

extern "C" void kernel_launch(void* const* d_in, const int* in_sizes, int n_in,
                              void* d_out, int out_size, void* d_ws, size_t ws_size,
                              hipStream_t stream) {
  const float* X  = (const float*)d_in[0];
  const float* Wq = (const float*)d_in[1];
  const float* Wk = (const float*)d_in[2];
  const float* Wv = (const float*)d_in[3];

  const size_t nrow = (size_t)NB * SEQ;              // 8192
  short* qws  = (short*)d_ws;                        // [8192][64] bf16
  short* kws  = qws + nrow * DH;
  short* vtws = kws + nrow * DH;
  const size_t qkv_bytes = 3 * nrow * DH * sizeof(short);   // 3.15 MB

  // layout: qkv | po [8192][nck][64] f32 | pm | pl   (wbf aliases po start;
  // wbf is dead before flash overwrites it)
  int nck, cht, ckshift;
  {
    const size_t need4 = qkv_bytes + nrow * 4 * (DH + 2) * sizeof(float);
    if (ws_size >= need4) { nck = 4; cht = 8;  ckshift = 9;  }
    else                  { nck = 1; cht = 32; ckshift = 11; }
  }
  float* po  = (float*)(vtws + nrow * DH);
  short* wbf = (short*)po;
  float* pm  = po + nrow * nck * DH;
  float* pl  = pm + nrow * nck;

  wconv_kernel<<<dim3(96), 256, 0, stream>>>(Wq, Wk, Wv, wbf);
  proj_kernel<<<dim3(NB * SEQ / 32), 512, 0, stream>>>(X, wbf, qws, kws, vtws);
  flash_kernel<<<dim3(SEQ / 64, nck, NB), 256, 0, stream>>>(qws, kws, vtws, po, pm, pl, nck, cht);
  merge_kernel<<<dim3(NB * SEQ * DH / 256), 256, 0, stream>>>(po, pm, pl, (float*)d_out, nck, ckshift);
}

// Round 24
// 48.135 us; speedup vs baseline: 1.0097x; 1.0097x over previous
//
#include <hip/hip_runtime.h>
#include <hip/hip_bf16.h>

// Problem constants
#define NB 4
#define SEQ 2048
#define DM 1024
#define DH 64

typedef __attribute__((ext_vector_type(8))) short bf16x8;
typedef __attribute__((ext_vector_type(4))) float f32x4;
typedef __attribute__((ext_vector_type(4))) short short4v;

__device__ inline short f2bf(float f) {
  union { float f; unsigned u; } x; x.f = f;
  unsigned r = x.u + 0x7FFFu + ((x.u >> 16) & 1u);
  return (short)(r >> 16);
}

// ---------------------------------------------------------------------------
// Kernel 0: W fp32 -> bf16, once. wbf[192][1024]: rows 0-63 Wq, 64-127 Wk,
// 128-191 Wv.
// ---------------------------------------------------------------------------
__global__ __launch_bounds__(256) void wconv_kernel(
    const float* __restrict__ Wq, const float* __restrict__ Wk,
    const float* __restrict__ Wv, short* __restrict__ wbf)
{
  const int tid = blockIdx.x * 256 + threadIdx.x;
  const int base = tid * 8;
  const int row = base >> 10;          // 0..191
  const int col = base & 1023;
  const float* src = (row < 64) ? Wq : (row < 128) ? Wk : Wv;
  src += (size_t)(row & 63) * DM + col;
  f32x4 f0 = ((const f32x4*)src)[0];
  f32x4 f1 = ((const f32x4*)src)[1];
  bf16x8 h = { f2bf(f0[0]), f2bf(f0[1]), f2bf(f0[2]), f2bf(f0[3]),
               f2bf(f1[0]), f2bf(f1[1]), f2bf(f1[2]), f2bf(f1[3]) };
  *(bf16x8*)(wbf + (size_t)row * DM + col) = h;
}

// ---------------------------------------------------------------------------
// Kernel 1: QKV projection (best-measured config). Depth-2 pipelined,
// 256 blocks x 512 threads, 32x192 tile, BK=64, 16 iters; vectorized V^T
// epilogue (one 8B store per frag, reg j -> row rowb+j consecutive in
// [dh][s] layout).
// ---------------------------------------------------------------------------
__global__ __launch_bounds__(512) void proj_kernel(
    const float* __restrict__ X, const short* __restrict__ wbf,
    short* __restrict__ qout, short* __restrict__ kout,
    short* __restrict__ vtout)
{
  __shared__ short x_lds[2][32][80];
  __shared__ short w_lds[2][192][80];

  const int t = threadIdx.x;
  const int l = t & 63;
  const int w = t >> 6;                 // 0..7
  const int m0 = blockIdx.x * 32;

  f32x4 acc[3];
#pragma unroll
  for (int i = 0; i < 3; i++) acc[i] = (f32x4){0.f, 0.f, 0.f, 0.f};

  const int xr = t >> 4;                // 0..31
  const int xc = (t & 15) * 4;          // float cols 0..60
  const int wr = t >> 3;                // 0..63
  const int wc = (t & 7) * 8;           // bf16 cols 0..56

  const float* xsrc  = X   + (size_t)(m0 + xr) * DM + xc;
  const short* wsrc0 = wbf + (size_t)(wr)       * DM + wc;
  const short* wsrc1 = wbf + (size_t)(64 + wr)  * DM + wc;
  const short* wsrc2 = wbf + (size_t)(128 + wr) * DM + wc;

  // prologue: stage k-step 0 into buf0
  {
    f32x4 f = *(const f32x4*)xsrc;
    short4v h = { f2bf(f[0]), f2bf(f[1]), f2bf(f[2]), f2bf(f[3]) };
    *(short4v*)&x_lds[0][xr][xc] = h;
    *(bf16x8*)&w_lds[0][wr][wc]       = *(const bf16x8*)wsrc0;
    *(bf16x8*)&w_lds[0][64 + wr][wc]  = *(const bf16x8*)wsrc1;
    *(bf16x8*)&w_lds[0][128 + wr][wc] = *(const bf16x8*)wsrc2;
  }
  // issue k-step 1 loads into rA (in flight across the barrier)
  f32x4 xA = *(const f32x4*)(xsrc + 64);
  bf16x8 wA0 = *(const bf16x8*)(wsrc0 + 64);
  bf16x8 wA1 = *(const bf16x8*)(wsrc1 + 64);
  bf16x8 wA2 = *(const bf16x8*)(wsrc2 + 64);
  f32x4 xB;
  bf16x8 wB0, wB1, wB2;
  __syncthreads();

#pragma unroll
  for (int it = 0; it < 16; it++) {
    const int buf = it & 1;
    const int k2 = (it + 2) * 64;

    // issue loads for iter it+2 (static ping-pong: even->rB, odd->rA)
    if ((it & 1) == 0) {
      if (it + 2 < 16) {
        xB  = *(const f32x4*)(xsrc + k2);
        wB0 = *(const bf16x8*)(wsrc0 + k2);
        wB1 = *(const bf16x8*)(wsrc1 + k2);
        wB2 = *(const bf16x8*)(wsrc2 + k2);
      }
    } else {
      if (it + 2 < 16) {
        xA  = *(const f32x4*)(xsrc + k2);
        wA0 = *(const bf16x8*)(wsrc0 + k2);
        wA1 = *(const bf16x8*)(wsrc1 + k2);
        wA2 = *(const bf16x8*)(wsrc2 + k2);
      }
    }

    // compute from lds[buf]
    const short* xp = &x_lds[buf][(w & 1) * 16 + (l & 15)][(l >> 4) << 3];
    bf16x8 a0 = *(const bf16x8*)xp;
    bf16x8 a1 = *(const bf16x8*)(xp + 32);
#pragma unroll
    for (int nf = 0; nf < 3; nf++) {
      const int cf = (w >> 1) * 3 + nf;
      const short* wp = &w_lds[buf][cf * 16 + (l & 15)][(l >> 4) << 3];
      bf16x8 b0 = *(const bf16x8*)wp;
      bf16x8 b1 = *(const bf16x8*)(wp + 32);
      acc[nf] = __builtin_amdgcn_mfma_f32_16x16x32_bf16(a0, b0, acc[nf], 0, 0, 0);
      acc[nf] = __builtin_amdgcn_mfma_f32_16x16x32_bf16(a1, b1, acc[nf], 0, 0, 0);
    }

    // ds_write iter it+1's regs (issued one full iteration ago)
    if (it < 15) {
      if ((it & 1) == 0) {
        short4v h = { f2bf(xA[0]), f2bf(xA[1]), f2bf(xA[2]), f2bf(xA[3]) };
        *(short4v*)&x_lds[buf ^ 1][xr][xc] = h;
        *(bf16x8*)&w_lds[buf ^ 1][wr][wc]       = wA0;
        *(bf16x8*)&w_lds[buf ^ 1][64 + wr][wc]  = wA1;
        *(bf16x8*)&w_lds[buf ^ 1][128 + wr][wc] = wA2;
      } else {
        short4v h = { f2bf(xB[0]), f2bf(xB[1]), f2bf(xB[2]), f2bf(xB[3]) };
        *(short4v*)&x_lds[buf ^ 1][xr][xc] = h;
        *(bf16x8*)&w_lds[buf ^ 1][wr][wc]       = wB0;
        *(bf16x8*)&w_lds[buf ^ 1][64 + wr][wc]  = wB1;
        *(bf16x8*)&w_lds[buf ^ 1][128 + wr][wc] = wB2;
      }
    }
    __syncthreads();
  }

  // epilogue: C row=(lane>>4)*4+reg, col=cf*16+(lane&15)  [m89]
  const int rowb = m0 + (w & 1) * 16 + ((l >> 4) << 2);
#pragma unroll
  for (int nf = 0; nf < 3; nf++) {
    const int c = ((w >> 1) * 3 + nf) * 16 + (l & 15);
    if (c < 64) {
#pragma unroll
      for (int j = 0; j < 4; j++)
        qout[(rowb + j) * DH + c] = f2bf(acc[nf][j] * 0.03125f);  // 1/32
    } else if (c < 128) {
#pragma unroll
      for (int j = 0; j < 4; j++)
        kout[(rowb + j) * DH + (c - 64)] = f2bf(acc[nf][j]);
    } else {
      // V^T: regs j=0..3 are rows rowb..rowb+3 -> one 8B store.
      const int b = rowb >> 11, s = rowb & (SEQ - 1);
      short4v h = { f2bf(acc[nf][0]), f2bf(acc[nf][1]),
                    f2bf(acc[nf][2]), f2bf(acc[nf][3]) };
      *(short4v*)(vtout + (size_t)b * DH * SEQ + (size_t)(c - 128) * SEQ + s) = h;
    }
  }
}

// ---------------------------------------------------------------------------
// Kernel 2: split-KV causal flash (nck=4/cht=8 proven best).
// ---------------------------------------------------------------------------
__global__ __launch_bounds__(256) void flash_kernel(
    const short* __restrict__ qin, const short* __restrict__ kin,
    const short* __restrict__ vtin, float* __restrict__ po,
    float* __restrict__ pm, float* __restrict__ pl,
    const int nck, const int cht)
{
  __shared__ short k_lds[2][64][72];
  __shared__ short vt_lds[2][64][72];
  __shared__ short p_lds[4][16][72];

  const int qt = blockIdx.x;
  const int ck = blockIdx.y;
  const int t0 = ck * cht;
  if (t0 > qt) return;
  const int b = blockIdx.z;

  const int t = threadIdx.x;
  const int l = t & 63;
  const int w = t >> 6;
  const int q0 = qt * 64;
  const int tend = min(t0 + cht, qt + 1);

  const short* qb = qin  + (size_t)b * SEQ * DH;
  const short* kb = kin  + (size_t)b * SEQ * DH;
  const short* vb = vtin + (size_t)b * DH * SEQ;

  const short* qr = qb + (size_t)(q0 + w * 16 + (l & 15)) * DH + ((l >> 4) << 3);
  const bf16x8 qf0 = *(const bf16x8*)qr;
  const bf16x8 qf1 = *(const bf16x8*)(qr + 32);

  f32x4 o[4];
#pragma unroll
  for (int i = 0; i < 4; i++) o[i] = (f32x4){0.f, 0.f, 0.f, 0.f};
  float m_run[4] = {-1e30f, -1e30f, -1e30f, -1e30f};
  float l_run[4] = {0.f, 0.f, 0.f, 0.f};

  const int sr = t >> 3;
  const int sc = (t & 7) * 8;

  {
    const int j0 = t0 * 64;
#pragma unroll
    for (int i = 0; i < 2; i++) {
      const int r = sr + i * 32;
      *(bf16x8*)&k_lds[0][r][sc]  = *(const bf16x8*)(kb + (size_t)(j0 + r) * DH + sc);
      *(bf16x8*)&vt_lds[0][r][sc] = *(const bf16x8*)(vb + (size_t)r * SEQ + j0 + sc);
    }
  }
  __syncthreads();

  for (int tt = t0; tt < tend; tt++) {
    const int bi = (tt - t0) & 1;
    const int j0 = tt * 64;
    const bool pf = (tt + 1 < tend);

    bf16x8 kpf0, kpf1, vpf0, vpf1;
    if (pf) {
      const int j1 = j0 + 64;
      kpf0 = *(const bf16x8*)(kb + (size_t)(j1 + sr) * DH + sc);
      kpf1 = *(const bf16x8*)(kb + (size_t)(j1 + sr + 32) * DH + sc);
      vpf0 = *(const bf16x8*)(vb + (size_t)sr * SEQ + j1 + sc);
      vpf1 = *(const bf16x8*)(vb + (size_t)(sr + 32) * SEQ + j1 + sc);
    }

    f32x4 s[4];
#pragma unroll
    for (int nf = 0; nf < 4; nf++) {
      const short* kr = &k_lds[bi][nf * 16 + (l & 15)][(l >> 4) << 3];
      bf16x8 b0 = *(const bf16x8*)kr;
      bf16x8 b1 = *(const bf16x8*)(kr + 32);
      f32x4 a = (f32x4){0.f, 0.f, 0.f, 0.f};
      a = __builtin_amdgcn_mfma_f32_16x16x32_bf16(qf0, b0, a, 0, 0, 0);
      a = __builtin_amdgcn_mfma_f32_16x16x32_bf16(qf1, b1, a, 0, 0, 0);
      s[nf] = a;
    }

    {
      const int growb = q0 + w * 16 + ((l >> 4) << 2);
#pragma unroll
      for (int nf = 0; nf < 4; nf++) {
        const int gcol = j0 + nf * 16 + (l & 15);
#pragma unroll
        for (int j = 0; j < 4; j++)
          if (gcol > growb + j) s[nf][j] = -1e30f;
      }
    }

    float alpha[4];
#pragma unroll
    for (int j = 0; j < 4; j++) {
      float tm = fmaxf(fmaxf(s[0][j], s[1][j]), fmaxf(s[2][j], s[3][j]));
      tm = fmaxf(tm, __shfl_xor(tm, 1));
      tm = fmaxf(tm, __shfl_xor(tm, 2));
      tm = fmaxf(tm, __shfl_xor(tm, 4));
      tm = fmaxf(tm, __shfl_xor(tm, 8));
      const float mn = fmaxf(m_run[j], tm);
      alpha[j] = exp2f((m_run[j] - mn) * 1.44269504f);
      m_run[j] = mn;
      float rs = 0.f;
#pragma unroll
      for (int nf = 0; nf < 4; nf++) {
        const float p = exp2f((s[nf][j] - mn) * 1.44269504f);
        s[nf][j] = p;
        rs += p;
      }
      rs += __shfl_xor(rs, 1);
      rs += __shfl_xor(rs, 2);
      rs += __shfl_xor(rs, 4);
      rs += __shfl_xor(rs, 8);
      l_run[j] = l_run[j] * alpha[j] + rs;
    }
#pragma unroll
    for (int df = 0; df < 4; df++)
#pragma unroll
      for (int j = 0; j < 4; j++) o[df][j] *= alpha[j];

#pragma unroll
    for (int nf = 0; nf < 4; nf++)
#pragma unroll
      for (int j = 0; j < 4; j++)
        p_lds[w][((l >> 4) << 2) + j][nf * 16 + (l & 15)] = f2bf(s[nf][j]);

    asm volatile("s_waitcnt lgkmcnt(0)" ::: "memory");
    __builtin_amdgcn_sched_barrier(0);

#pragma unroll
    for (int ks = 0; ks < 2; ks++) {
      const short* pr = &p_lds[w][l & 15][ks * 32 + ((l >> 4) << 3)];
      const bf16x8 pa = *(const bf16x8*)pr;
#pragma unroll
      for (int df = 0; df < 4; df++) {
        const short* vr = &vt_lds[bi][df * 16 + (l & 15)][ks * 32 + ((l >> 4) << 3)];
        const bf16x8 vf = *(const bf16x8*)vr;
        o[df] = __builtin_amdgcn_mfma_f32_16x16x32_bf16(pa, vf, o[df], 0, 0, 0);
      }
    }

    if (pf) {
      *(bf16x8*)&k_lds[bi ^ 1][sr][sc]       = kpf0;
      *(bf16x8*)&k_lds[bi ^ 1][sr + 32][sc]  = kpf1;
      *(bf16x8*)&vt_lds[bi ^ 1][sr][sc]      = vpf0;
      *(bf16x8*)&vt_lds[bi ^ 1][sr + 32][sc] = vpf1;
    }
    __syncthreads();
  }

  const int rowb = q0 + w * 16 + ((l >> 4) << 2);
#pragma unroll
  for (int j = 0; j < 4; j++) {
    const size_t rowg = (size_t)b * SEQ + rowb + j;
#pragma unroll
    for (int df = 0; df < 4; df++)
      po[(rowg * nck + ck) * DH + df * 16 + (l & 15)] = o[df][j];
    if ((l & 15) == 0) {
      pm[rowg * nck + ck] = m_run[j];
      pl[rowg * nck + ck] = l_run[j];
    }
  }
}

// ---------------------------------------------------------------------------
// Kernel 3: merge partials. ckshift = log2(cht*64).
// ---------------------------------------------------------------------------
__global__ __launch_bounds__(256) void merge_kernel(
    const float* __restrict__ po, const float* __restrict__ pm,
    const float* __restrict__ pl, float* __restrict__ out,
    const int nck, const int ckshift)
{
  const int gid = blockIdx.x * 256 + threadIdx.x;
  const int r = gid >> 6;
  const int d = gid & 63;
  const int s = r & (SEQ - 1);
  const int C = (s >> ckshift) + 1;

  float m = -1e30f;
  for (int c = 0; c < C; c++) m = fmaxf(m, pm[r * nck + c]);
  float den = 0.f, num = 0.f;
  for (int c = 0; c < C; c++) {
    const float wgt = exp2f((pm[r * nck + c] - m) * 1.44269504f);
    den += pl[r * nck + c] * wgt;
    num += po[(size_t)(r * nck + c) * DH + d] * wgt;
  }
  out[gid] = num / den;
}

extern "C" void kernel_launch(void* const* d_in, const int* in_sizes, int n_in,
                              void* d_out, int out_size, void* d_ws, size_t ws_size,
                              hipStream_t stream) {
  const float* X  = (const float*)d_in[0];
  const float* Wq = (const float*)d_in[1];
  const float* Wk = (const float*)d_in[2];
  const float* Wv = (const float*)d_in[3];

  const size_t nrow = (size_t)NB * SEQ;              // 8192
  short* qws  = (short*)d_ws;                        // [8192][64] bf16
  short* kws  = qws + nrow * DH;
  short* vtws = kws + nrow * DH;
  const size_t qkv_bytes = 3 * nrow * DH * sizeof(short);   // 3.15 MB

  // layout: qkv | po [8192][nck][64] f32 | pm | pl   (wbf aliases po start;
  // wbf is dead before flash overwrites it)
  int nck, cht, ckshift;
  {
    const size_t need4 = qkv_bytes + nrow * 4 * (DH + 2) * sizeof(float);
    if (ws_size >= need4) { nck = 4; cht = 8;  ckshift = 9;  }
    else                  { nck = 1; cht = 32; ckshift = 11; }
  }
  float* po  = (float*)(vtws + nrow * DH);
  short* wbf = (short*)po;
  float* pm  = po + nrow * nck * DH;
  float* pl  = pm + nrow * nck;

  wconv_kernel<<<dim3(96), 256, 0, stream>>>(Wq, Wk, Wv, wbf);
  proj_kernel<<<dim3(NB * SEQ / 32), 512, 0, stream>>>(X, wbf, qws, kws, vtws);
  flash_kernel<<<dim3(SEQ / 64, nck, NB), 256, 0, stream>>>(qws, kws, vtws, po, pm, pl, nck, cht);
  merge_kernel<<<dim3(NB * SEQ * DH / 256), 256, 0, stream>>>(po, pm, pl, (float*)d_out, nck, ckshift);
}